// Round 6
// baseline (129.884 us; speedup 1.0000x reference)
//
#include <hip/hip_runtime.h>
#include <cstdint>

#define E_DIM   1024
#define DH      32
#define M_FEAT  256
#define BT      16384

typedef __attribute__((ext_vector_type(8))) _Float16 f16x8;
typedef __attribute__((ext_vector_type(4))) float f32x4;

// ws layout (shorts=fp16): proj W in MFMA-fragment order, flat = (nt*32 + sub)*512 + lane*8
// single fp16 panel (no l-term for weights), 128 KB total

__device__ __forceinline__ unsigned packh2(_Float16 a, _Float16 b) {
    union { _Float16 h[2]; unsigned u; } t;
    t.h[0] = a; t.h[1] = b;
    return t.u;
}

// x/z 2-term fp16 split: h = fp16_rne(f), l = fp16_rne(f - h)
__device__ __forceinline__ void splitf16_2(float f0, float f1, unsigned& ph, unsigned& pl) {
    _Float16 h0 = (_Float16)f0, h1 = (_Float16)f1;
    float l0 = f0 - (float)h0, l1 = f1 - (float)h1;
    ph = packh2(h0, h1);
    pl = packh2((_Float16)l0, (_Float16)l1);
}

__device__ __forceinline__ void splitf16_8(const float4& a, const float4& b,
                                           uint4& uh, uint4& ul) {
    splitf16_2(a.x, a.y, uh.x, ul.x);
    splitf16_2(a.z, a.w, uh.y, ul.y);
    splitf16_2(b.x, b.y, uh.z, ul.z);
    splitf16_2(b.z, b.w, uh.w, ul.w);
}

// ---------- prep: 32 blocks, each a 64-k half-slab; LDS transpose -> fp16 fragment order ----------
__global__ __launch_bounds__(256) void k_prep(
    const float* __restrict__ Wq, const float* __restrict__ Wk,
    short* __restrict__ ws)
{
    __shared__ float wlds[64 * 36];    // [k 0..63][n 0..31], stride 36 floats
    const int b = blockIdx.x, tid = threadIdx.x;
    const float* __restrict__ src = (b < 16) ? Wq : Wk;
    const int k0 = (b & 15) * 64;
    const int nbase = (b < 16) ? 0 : 32;
#pragma unroll
    for (int it = 0; it < 2; ++it) {               // coalesced read 64x32 floats
        int f = it * 256 + tid;                    // float4 index
        int k = f >> 3, c4 = f & 7;
        float4 v = *(const float4*)(src + (size_t)(k0 + k) * DH + c4 * 4);
        *(float4*)&wlds[k * 36 + c4 * 4] = v;
    }
    __syncthreads();
    const int n = tid >> 3, kq = tid & 7;
    const int n_g = nbase + n;
    const int nt = n_g >> 4, ln = n_g & 15;
#pragma unroll
    for (int rep = 0; rep < 2; ++rep) {
        int kk = rep * 8 + kq;                     // k-quad within this 64-slab
        int k_g = k0 + kk * 4;
        float f0 = wlds[(kk * 4 + 0) * 36 + n];
        float f1 = wlds[(kk * 4 + 1) * 36 + n];
        float f2 = wlds[(kk * 4 + 2) * 36 + n];
        float f3 = wlds[(kk * 4 + 3) * 36 + n];
        uint2 ph;
        ph.x = packh2((_Float16)f0, (_Float16)f1); // RNE fp16, err <= 2^-12 rel
        ph.y = packh2((_Float16)f2, (_Float16)f3);
        int sub = k_g >> 5;                        // global 32-k subchunk 0..31
        int gq = (k_g >> 3) & 3, j0 = k_g & 7;
        int lane = gq * 16 + ln;
        size_t flat = ((size_t)(nt * 32 + sub)) * 512 + lane * 8 + j0;
        *(uint2*)(ws + flat) = ph;
    }
}

// ---------- main: 1-wave blocks, 16 tokens/wave, ZERO barriers ----------
// Each wave: stages own x rows (intra-wave LDS transpose, lgkm-ordered only),
// computes all 64 proj cols (4 n-tiles) -> z & lnA register-local (shfl reduce),
// z transpose via private LDS tile, then all 256 features in 4 reg groups.
#define XS2 136   // x LDS row stride in shorts (128 data + 8 pad)
#define ZSF 36    // z LDS row stride in floats (16B-aligned, even bank spread)

__global__ __launch_bounds__(64, 2) void k_main(
    const float* __restrict__ x, const float* __restrict__ bq,
    const float* __restrict__ bk, const short* __restrict__ ws,
    const float* __restrict__ w, float* __restrict__ out)
{
    __shared__ __align__(16) short xh_s[2][16 * XS2];
    __shared__ __align__(16) short xl_s[2][16 * XS2];
    __shared__ __align__(16) float zf_s[16 * ZSF];

    const int lane = threadIdx.x;      // 0..63 (one wave per block)
    const int ln15 = lane & 15;
    const int g    = lane >> 4;        // 0..3
    const long t0  = (long)blockIdx.x * 16;

    // -------- Phase 1: C[16 tok][64] = x @ [Wq|Wk] (fp16 2-pass), barrier-free --------
    f32x4 acc[4];
#pragma unroll
    for (int nt = 0; nt < 4; ++nt) acc[nt] = (f32x4){0.f, 0.f, 0.f, 0.f};

    const short* wpB = ws + lane * 8;  // + (nt*32 + fi)*512

    // staging roles: kq = ln15 (k-chunk of 8 floats), r4 = g (row in 4-row group)
    const float* xrow0 = x + (t0 + 0 * 4 + g) * (size_t)E_DIM + ln15 * 8;
    const float* xrow1 = x + (t0 + 1 * 4 + g) * (size_t)E_DIM + ln15 * 8;
    const float* xrow2 = x + (t0 + 2 * 4 + g) * (size_t)E_DIM + ln15 * 8;
    const float* xrow3 = x + (t0 + 3 * 4 + g) * (size_t)E_DIM + ln15 * 8;

    float4 xb[8];
    f16x8 bg[3][4];

    // prologue: pair 0 loads -> stage buf0; issue pair 1; B(0),B(1) into ring
    xb[0] = *(const float4*)(xrow0 + 0); xb[1] = *(const float4*)(xrow0 + 4);
    xb[2] = *(const float4*)(xrow1 + 0); xb[3] = *(const float4*)(xrow1 + 4);
    xb[4] = *(const float4*)(xrow2 + 0); xb[5] = *(const float4*)(xrow2 + 4);
    xb[6] = *(const float4*)(xrow3 + 0); xb[7] = *(const float4*)(xrow3 + 4);
#pragma unroll
    for (int nt = 0; nt < 4; ++nt)
        bg[0][nt] = *(const f16x8*)(wpB + ((size_t)nt * 32 + 0) * 512);
#pragma unroll
    for (int nt = 0; nt < 4; ++nt)
        bg[1][nt] = *(const f16x8*)(wpB + ((size_t)nt * 32 + 1) * 512);
    {
        uint4 uh, ul;
        splitf16_8(xb[0], xb[1], uh, ul);
        *(uint4*)&xh_s[0][(0 * 4 + g) * XS2 + ln15 * 8] = uh;
        *(uint4*)&xl_s[0][(0 * 4 + g) * XS2 + ln15 * 8] = ul;
        splitf16_8(xb[2], xb[3], uh, ul);
        *(uint4*)&xh_s[0][(1 * 4 + g) * XS2 + ln15 * 8] = uh;
        *(uint4*)&xl_s[0][(1 * 4 + g) * XS2 + ln15 * 8] = ul;
        splitf16_8(xb[4], xb[5], uh, ul);
        *(uint4*)&xh_s[0][(2 * 4 + g) * XS2 + ln15 * 8] = uh;
        *(uint4*)&xl_s[0][(2 * 4 + g) * XS2 + ln15 * 8] = ul;
        splitf16_8(xb[6], xb[7], uh, ul);
        *(uint4*)&xh_s[0][(3 * 4 + g) * XS2 + ln15 * 8] = uh;
        *(uint4*)&xl_s[0][(3 * 4 + g) * XS2 + ln15 * 8] = ul;
    }
    xb[0] = *(const float4*)(xrow0 + 128); xb[1] = *(const float4*)(xrow0 + 132);
    xb[2] = *(const float4*)(xrow1 + 128); xb[3] = *(const float4*)(xrow1 + 132);
    xb[4] = *(const float4*)(xrow2 + 128); xb[5] = *(const float4*)(xrow2 + 132);
    xb[6] = *(const float4*)(xrow3 + 128); xb[7] = *(const float4*)(xrow3 + 132);

#pragma unroll
    for (int p = 0; p < 8; ++p) {
#pragma unroll
        for (int j = 0; j < 4; ++j) {
            const int fi = p * 4 + j;
            if (fi + 2 < 32) {          // B ring prefetch, distance 2 (covers L2 latency)
#pragma unroll
                for (int nt = 0; nt < 4; ++nt)
                    bg[(fi + 2) % 3][nt] =
                        *(const f16x8*)(wpB + ((size_t)nt * 32 + fi + 2) * 512);
            }
            f16x8 ah = *(const f16x8*)&xh_s[p & 1][ln15 * XS2 + j * 32 + g * 8];
            f16x8 al = *(const f16x8*)&xl_s[p & 1][ln15 * XS2 + j * 32 + g * 8];
#pragma unroll
            for (int nt = 0; nt < 4; ++nt)
                acc[nt] = __builtin_amdgcn_mfma_f32_16x16x32_f16(ah, bg[fi % 3][nt], acc[nt], 0, 0, 0);
#pragma unroll
            for (int nt = 0; nt < 4; ++nt)
                acc[nt] = __builtin_amdgcn_mfma_f32_16x16x32_f16(al, bg[fi % 3][nt], acc[nt], 0, 0, 0);
        }
        if (p < 7) {
            // stage pair p+1 (regs loaded a full phase ago) into buf (p+1)&1
            uint4 uh, ul;
            splitf16_8(xb[0], xb[1], uh, ul);
            *(uint4*)&xh_s[(p + 1) & 1][(0 * 4 + g) * XS2 + ln15 * 8] = uh;
            *(uint4*)&xl_s[(p + 1) & 1][(0 * 4 + g) * XS2 + ln15 * 8] = ul;
            splitf16_8(xb[2], xb[3], uh, ul);
            *(uint4*)&xh_s[(p + 1) & 1][(1 * 4 + g) * XS2 + ln15 * 8] = uh;
            *(uint4*)&xl_s[(p + 1) & 1][(1 * 4 + g) * XS2 + ln15 * 8] = ul;
            splitf16_8(xb[4], xb[5], uh, ul);
            *(uint4*)&xh_s[(p + 1) & 1][(2 * 4 + g) * XS2 + ln15 * 8] = uh;
            *(uint4*)&xl_s[(p + 1) & 1][(2 * 4 + g) * XS2 + ln15 * 8] = ul;
            splitf16_8(xb[6], xb[7], uh, ul);
            *(uint4*)&xh_s[(p + 1) & 1][(3 * 4 + g) * XS2 + ln15 * 8] = uh;
            *(uint4*)&xl_s[(p + 1) & 1][(3 * 4 + g) * XS2 + ln15 * 8] = ul;
            if (p < 6) {                // issue pair p+2 (distance 2: ~full phase of slack)
                xb[0] = *(const float4*)(xrow0 + (p + 2) * 128);
                xb[1] = *(const float4*)(xrow0 + (p + 2) * 128 + 4);
                xb[2] = *(const float4*)(xrow1 + (p + 2) * 128);
                xb[3] = *(const float4*)(xrow1 + (p + 2) * 128 + 4);
                xb[4] = *(const float4*)(xrow2 + (p + 2) * 128);
                xb[5] = *(const float4*)(xrow2 + (p + 2) * 128 + 4);
                xb[6] = *(const float4*)(xrow3 + (p + 2) * 128);
                xb[7] = *(const float4*)(xrow3 + (p + 2) * 128 + 4);
            }
        }
    }

    // -------- Phase 2+3 (register-local): bias, z -> private LDS tile, lnA via shfl --------
    // C/D layout: acc[nt][r] = C[row g*4+r][col nt*16+ln15]; q = cols 0..31, k = 32..63
    const float b0 = bq[ln15], b1 = bq[16 + ln15];
    const float b2 = bk[ln15], b3 = bk[16 + ln15];
    float lnAv[4];
#pragma unroll
    for (int r = 0; r < 4; ++r) {
        float q0 = acc[0][r] + b0, q1 = acc[1][r] + b1;
        float k0 = acc[2][r] + b2, k1 = acc[3][r] + b3;
        zf_s[(g * 4 + r) * ZSF + ln15]      = q0 + k0;
        zf_s[(g * 4 + r) * ZSF + 16 + ln15] = q1 + k1;
        float pw = q0 * q0 + q1 * q1 + k0 * k0 + k1 * k1;
        pw += __shfl_xor(pw, 1);
        pw += __shfl_xor(pw, 2);
        pw += __shfl_xor(pw, 4);
        pw += __shfl_xor(pw, 8);       // reduce over the 16-lane (ln15) group
        lnAv[r] = -0.5f * pw;
    }

    // -------- Phase 4+5: S = z @ w^T, R = 0.5(exp(lnA+s)+exp(lnA-s)), 4 nt-groups --------
    // z A-fragment read (intra-wave transpose; lgkm in-order, no barrier)
    float4 za = *(const float4*)&zf_s[ln15 * ZSF + g * 8];
    float4 zb = *(const float4*)&zf_s[ln15 * ZSF + g * 8 + 4];
    uint4 zuh, zul;
    splitf16_8(za, zb, zuh, zul);
    f16x8 a_h = __builtin_bit_cast(f16x8, zuh);
    f16x8 a_l = __builtin_bit_cast(f16x8, zul);

    float4 wf[2][8];
#pragma unroll
    for (int t = 0; t < 4; ++t) {      // group 0 feature loads
        const int nf = t * 16 + ln15;
        wf[0][2 * t]     = *(const float4*)(w + (size_t)nf * DH + g * 8);
        wf[0][2 * t + 1] = *(const float4*)(w + (size_t)nf * DH + g * 8 + 4);
    }
#pragma unroll
    for (int gi = 0; gi < 4; ++gi) {
        if (gi < 3) {                  // distance-1 group prefetch
#pragma unroll
            for (int t = 0; t < 4; ++t) {
                const int nf = ((gi + 1) * 4 + t) * 16 + ln15;
                wf[(gi + 1) & 1][2 * t]     = *(const float4*)(w + (size_t)nf * DH + g * 8);
                wf[(gi + 1) & 1][2 * t + 1] = *(const float4*)(w + (size_t)nf * DH + g * 8 + 4);
            }
        }
#pragma unroll
        for (int t = 0; t < 4; ++t) {
            uint4 uw;
            uw.x = packh2((_Float16)wf[gi & 1][2 * t].x,     (_Float16)wf[gi & 1][2 * t].y);
            uw.y = packh2((_Float16)wf[gi & 1][2 * t].z,     (_Float16)wf[gi & 1][2 * t].w);
            uw.z = packh2((_Float16)wf[gi & 1][2 * t + 1].x, (_Float16)wf[gi & 1][2 * t + 1].y);
            uw.w = packh2((_Float16)wf[gi & 1][2 * t + 1].z, (_Float16)wf[gi & 1][2 * t + 1].w);
            f16x8 w8 = __builtin_bit_cast(f16x8, uw);
            f32x4 fa = (f32x4){0.f, 0.f, 0.f, 0.f};
            fa = __builtin_amdgcn_mfma_f32_16x16x32_f16(a_h, w8, fa, 0, 0, 0);
            fa = __builtin_amdgcn_mfma_f32_16x16x32_f16(a_l, w8, fa, 0, 0, 0);
            const int n = (gi * 4 + t) * 16 + ln15;
#pragma unroll
            for (int r = 0; r < 4; ++r) {
                float s = fa[r];
                float R = 0.5f * (__expf(lnAv[r] + s) + __expf(lnAv[r] - s));
                __builtin_nontemporal_store(R, &out[(t0 + g * 4 + r) * M_FEAT + n]);
            }
        }
    }
}

extern "C" void kernel_launch(void* const* d_in, const int* in_sizes, int n_in,
                              void* d_out, int out_size, void* d_ws, size_t ws_size,
                              hipStream_t stream) {
    const float* x  = (const float*)d_in[0];
    const float* Wq = (const float*)d_in[1];
    const float* bq = (const float*)d_in[2];
    const float* Wk = (const float*)d_in[3];
    const float* bk = (const float*)d_in[4];
    // d_in[5], d_in[6] = Wv, bv: dead in the reference
    const float* w  = (const float*)d_in[7];
    float* out = (float*)d_out;
    short* ws  = (short*)d_ws;   // 128 KB used (single fp16 weight panel)

    k_prep<<<dim3(32), dim3(256), 0, stream>>>(Wq, Wk, ws);
    k_main<<<dim3(BT / 16), dim3(64), 0, stream>>>(x, bq, bk, ws, w, out);
}

// Round 7
// 126.133 us; speedup vs baseline: 1.0297x; 1.0297x over previous
//
#include <hip/hip_runtime.h>
#include <cstdint>

#define E_DIM   1024
#define DH      32
#define M_FEAT  256
#define BT      16384

typedef __attribute__((ext_vector_type(8))) _Float16 f16x8;
typedef __attribute__((ext_vector_type(4))) float f32x4;

// ws layout (shorts=fp16): proj W in MFMA-fragment order, flat = (nt*32 + sub)*512 + lane*8
// single fp16 panel (no l-term for weights), 128 KB total

__device__ __forceinline__ unsigned packh2(_Float16 a, _Float16 b) {
    union { _Float16 h[2]; unsigned u; } t;
    t.h[0] = a; t.h[1] = b;
    return t.u;
}

// x/z 2-term fp16 split: h = fp16_rne(f), l = fp16_rne(f - h)
__device__ __forceinline__ void splitf16_2(float f0, float f1, unsigned& ph, unsigned& pl) {
    _Float16 h0 = (_Float16)f0, h1 = (_Float16)f1;
    float l0 = f0 - (float)h0, l1 = f1 - (float)h1;
    ph = packh2(h0, h1);
    pl = packh2((_Float16)l0, (_Float16)l1);
}

__device__ __forceinline__ void splitf16_8(const float4& a, const float4& b,
                                           uint4& uh, uint4& ul) {
    splitf16_2(a.x, a.y, uh.x, ul.x);
    splitf16_2(a.z, a.w, uh.y, ul.y);
    splitf16_2(b.x, b.y, uh.z, ul.z);
    splitf16_2(b.z, b.w, uh.w, ul.w);
}

// ---------- prep: 32 blocks, each a 64-k half-slab; LDS transpose -> fp16 fragment order ----------
__global__ __launch_bounds__(256) void k_prep(
    const float* __restrict__ Wq, const float* __restrict__ Wk,
    short* __restrict__ ws)
{
    __shared__ float wlds[64 * 36];    // [k 0..63][n 0..31], stride 36 floats
    const int b = blockIdx.x, tid = threadIdx.x;
    const float* __restrict__ src = (b < 16) ? Wq : Wk;
    const int k0 = (b & 15) * 64;
    const int nbase = (b < 16) ? 0 : 32;
#pragma unroll
    for (int it = 0; it < 2; ++it) {               // coalesced read 64x32 floats
        int f = it * 256 + tid;                    // float4 index
        int k = f >> 3, c4 = f & 7;
        float4 v = *(const float4*)(src + (size_t)(k0 + k) * DH + c4 * 4);
        *(float4*)&wlds[k * 36 + c4 * 4] = v;
    }
    __syncthreads();
    const int n = tid >> 3, kq = tid & 7;
    const int n_g = nbase + n;
    const int nt = n_g >> 4, ln = n_g & 15;
#pragma unroll
    for (int rep = 0; rep < 2; ++rep) {
        int kk = rep * 8 + kq;                     // k-quad within this 64-slab
        int k_g = k0 + kk * 4;
        float f0 = wlds[(kk * 4 + 0) * 36 + n];
        float f1 = wlds[(kk * 4 + 1) * 36 + n];
        float f2 = wlds[(kk * 4 + 2) * 36 + n];
        float f3 = wlds[(kk * 4 + 3) * 36 + n];
        uint2 ph;
        ph.x = packh2((_Float16)f0, (_Float16)f1); // RNE fp16, err <= 2^-12 rel
        ph.y = packh2((_Float16)f2, (_Float16)f3);
        int sub = k_g >> 5;                        // global 32-k subchunk 0..31
        int gq = (k_g >> 3) & 3, j0 = k_g & 7;
        int lane = gq * 16 + ln;
        size_t flat = ((size_t)(nt * 32 + sub)) * 512 + lane * 8 + j0;
        *(uint2*)(ws + flat) = ph;
    }
}

// ---------- main: 1024 blocks x 256 thr; TB=16 tokens; 4-way SPLIT-K projection ----------
// Wave wv owns K-range [wv*256, wv*256+256): A-fragments DIRECT from global (all 16
// loads issued upfront -> ONE vmcnt wait per wave), B via dist-3 register ring from
// the L2-resident fp16 panel. Partial C reduced across waves through LDS (1 barrier),
// then the proven 16-token tail (bias -> z/lnA -> feature MFMA -> exp/store).
#define QS 68    // qk row stride in floats
#define ZS 40    // z row stride in shorts

__global__ __launch_bounds__(256, 3) void k_main(
    const float* __restrict__ x, const float* __restrict__ bq,
    const float* __restrict__ bk, const short* __restrict__ ws,
    const float* __restrict__ w, float* __restrict__ out)
{
    __shared__ __align__(16) float red_s[4][4 * 256];  // 16 KB: [wv][nt*256 + g*64 + ln15*4 + r]
    __shared__ __align__(16) float qk_f[16 * QS];
    __shared__ __align__(16) short zh_s[16 * ZS];
    __shared__ __align__(16) short zl_s[16 * ZS];
    __shared__ float lnA_f[16];

    const int tid  = threadIdx.x;
    const int lane = tid & 63;
    const int wv   = __builtin_amdgcn_readfirstlane(tid >> 6);  // 0..3 (K-quarter)
    const int ln15 = lane & 15;
    const int g    = lane >> 4;                                  // 0..3
    const long t0  = (long)blockIdx.x * 16;

    // -------- Phase 1: partial C[16 tok][64] over K-quarter wv --------
    // A direct from global in MFMA layout: lane(ln15,g) = row ln15, k = g*8..g*8+7
    const float* __restrict__ xA = x + (t0 + ln15) * (size_t)E_DIM + wv * 256 + g * 8;
    float4 a[8][2];
#pragma unroll
    for (int fi = 0; fi < 8; ++fi) {               // ALL x loads issued upfront
        a[fi][0] = *(const float4*)(xA + fi * 32);
        a[fi][1] = *(const float4*)(xA + fi * 32 + 4);
    }
    // B ring, distance 3 (L2-resident panel); sub = wv*8 + fi
    const short* __restrict__ wpB = ws + (size_t)(wv * 8) * 512 + lane * 8;
    f16x8 bg[3][4];
#pragma unroll
    for (int q = 0; q < 3; ++q)
#pragma unroll
        for (int nt = 0; nt < 4; ++nt)
            bg[q][nt] = *(const f16x8*)(wpB + ((size_t)nt * 32 + q) * 512);

    f32x4 acc[4];
#pragma unroll
    for (int nt = 0; nt < 4; ++nt) acc[nt] = (f32x4){0.f, 0.f, 0.f, 0.f};

#pragma unroll
    for (int fi = 0; fi < 8; ++fi) {
        uint4 uh, ul;
        splitf16_8(a[fi][0], a[fi][1], uh, ul);
        f16x8 ah = __builtin_bit_cast(f16x8, uh);
        f16x8 al = __builtin_bit_cast(f16x8, ul);
#pragma unroll
        for (int nt = 0; nt < 4; ++nt)
            acc[nt] = __builtin_amdgcn_mfma_f32_16x16x32_f16(ah, bg[fi % 3][nt], acc[nt], 0, 0, 0);
#pragma unroll
        for (int nt = 0; nt < 4; ++nt)
            acc[nt] = __builtin_amdgcn_mfma_f32_16x16x32_f16(al, bg[fi % 3][nt], acc[nt], 0, 0, 0);
        if (fi + 3 < 8) {                          // refill ring slot just freed
#pragma unroll
            for (int nt = 0; nt < 4; ++nt)
                bg[fi % 3][nt] = *(const f16x8*)(wpB + ((size_t)nt * 32 + fi + 3) * 512);
        }
    }

    // partial -> LDS (r-contiguous so b128 writes)
#pragma unroll
    for (int nt = 0; nt < 4; ++nt)
        *(f32x4*)&red_s[wv][nt * 256 + g * 64 + ln15 * 4] = acc[nt];

    // issue feature-w fp32 fragment loads; reduce/barrier below cover their latency
    float4 wfa[4], wfb[4];
#pragma unroll
    for (int i = 0; i < 4; ++i) {
        const int nf = (wv * 4 + i) * 16 + ln15;    // feature 0..255
        wfa[i] = *(const float4*)(w + (size_t)nf * DH + g * 8);
        wfb[i] = *(const float4*)(w + (size_t)nf * DH + g * 8 + 4);
    }
    __syncthreads();

    // -------- Phase 2: wave wv reduces n-tile wv; +bias -> qk LDS --------
    // final layout identical to r0: lane(ln15,g) holds C[g*4+r][wv*16+ln15]
    f32x4 c = (f32x4){0.f, 0.f, 0.f, 0.f};
#pragma unroll
    for (int w2 = 0; w2 < 4; ++w2) {
        f32x4 t = *(const f32x4*)&red_s[w2][wv * 256 + g * 64 + ln15 * 4];
        c[0] += t[0]; c[1] += t[1]; c[2] += t[2]; c[3] += t[3];
    }
    const int nrow = wv * 16 + ln15;               // proj output column 0..63
    const float bias = (nrow < 32) ? bq[nrow] : bk[nrow - 32];
#pragma unroll
    for (int r = 0; r < 4; ++r)
        qk_f[(g * 4 + r) * QS + nrow] = c[r] + bias;
    __syncthreads();

    // -------- Phase 3: z = q+k (fp16 split), lnA = -0.5(|q|^2+|k|^2); 16 tok x 8 grp --------
    if (tid < 128) {
        const int tok = tid >> 3, grp = tid & 7;
        float4 qv = *(const float4*)&qk_f[tok * QS + grp * 4];
        float4 kv = *(const float4*)&qk_f[tok * QS + 32 + grp * 4];
        float z0 = qv.x + kv.x, z1 = qv.y + kv.y, z2 = qv.z + kv.z, z3 = qv.w + kv.w;
        float pw = qv.x*qv.x + qv.y*qv.y + qv.z*qv.z + qv.w*qv.w
                 + kv.x*kv.x + kv.y*kv.y + kv.z*kv.z + kv.w*kv.w;
        uint2 ph, pl;
        splitf16_2(z0, z1, ph.x, pl.x);
        splitf16_2(z2, z3, ph.y, pl.y);
        *(uint2*)&zh_s[tok * ZS + grp * 4] = ph;
        *(uint2*)&zl_s[tok * ZS + grp * 4] = pl;
        pw += __shfl_xor(pw, 1);
        pw += __shfl_xor(pw, 2);
        pw += __shfl_xor(pw, 4);
        if (grp == 0) lnA_f[tok] = -0.5f * pw;
    }
    __syncthreads();

    // -------- Phase 4: S[16 tok][256] = z @ w^T (fp16 2-pass); wave wv: features wv*64.. --------
    f32x4 facc[4];
#pragma unroll
    for (int i = 0; i < 4; ++i) facc[i] = (f32x4){0.f, 0.f, 0.f, 0.f};

    f16x8 a_h = *(const f16x8*)&zh_s[ln15 * ZS + g * 8];
    f16x8 a_l = *(const f16x8*)&zl_s[ln15 * ZS + g * 8];
#pragma unroll
    for (int i = 0; i < 4; ++i) {
        uint4 uw;
        uw.x = packh2((_Float16)wfa[i].x, (_Float16)wfa[i].y);
        uw.y = packh2((_Float16)wfa[i].z, (_Float16)wfa[i].w);
        uw.z = packh2((_Float16)wfb[i].x, (_Float16)wfb[i].y);
        uw.w = packh2((_Float16)wfb[i].z, (_Float16)wfb[i].w);
        f16x8 w8 = __builtin_bit_cast(f16x8, uw);
        facc[i] = __builtin_amdgcn_mfma_f32_16x16x32_f16(a_h, w8, facc[i], 0, 0, 0);
        facc[i] = __builtin_amdgcn_mfma_f32_16x16x32_f16(a_l, w8, facc[i], 0, 0, 0);
    }

    // -------- Phase 5: R = 0.5*(exp(lnA+s)+exp(lnA-s)) --------
    float lnAv[4];
#pragma unroll
    for (int r = 0; r < 4; ++r) lnAv[r] = lnA_f[g * 4 + r];

#pragma unroll
    for (int i = 0; i < 4; ++i) {
        const int n = (wv * 4 + i) * 16 + ln15;
#pragma unroll
        for (int r = 0; r < 4; ++r) {
            float s = facc[i][r];
            float R = 0.5f * (__expf(lnAv[r] + s) + __expf(lnAv[r] - s));
            __builtin_nontemporal_store(R, &out[(t0 + g * 4 + r) * M_FEAT + n]);
        }
    }
}

extern "C" void kernel_launch(void* const* d_in, const int* in_sizes, int n_in,
                              void* d_out, int out_size, void* d_ws, size_t ws_size,
                              hipStream_t stream) {
    const float* x  = (const float*)d_in[0];
    const float* Wq = (const float*)d_in[1];
    const float* bq = (const float*)d_in[2];
    const float* Wk = (const float*)d_in[3];
    const float* bk = (const float*)d_in[4];
    // d_in[5], d_in[6] = Wv, bv: dead in the reference
    const float* w  = (const float*)d_in[7];
    float* out = (float*)d_out;
    short* ws  = (short*)d_ws;   // 128 KB used (single fp16 weight panel)

    k_prep<<<dim3(32), dim3(256), 0, stream>>>(Wq, Wk, ws);
    k_main<<<dim3(BT / 16), dim3(256), 0, stream>>>(x, bq, bk, ws, w, out);
}

// Round 8
// 118.865 us; speedup vs baseline: 1.0927x; 1.0611x over previous
//
#include <hip/hip_runtime.h>
#include <cstdint>

#define E_DIM   1024
#define DH      32
#define M_FEAT  256
#define BT      16384

typedef __attribute__((ext_vector_type(8))) _Float16 f16x8;
typedef __attribute__((ext_vector_type(4))) float f32x4;

// ws layout (shorts=fp16): proj W in MFMA-fragment order, flat = (nt*32 + sub)*512 + lane*8
// single fp16 panel (no l-term for weights), 128 KB total

__device__ __forceinline__ unsigned packh2(_Float16 a, _Float16 b) {
    union { _Float16 h[2]; unsigned u; } t;
    t.h[0] = a; t.h[1] = b;
    return t.u;
}

// x/z 2-term fp16 split: h = fp16_rne(f), l = fp16_rne(f - h)
__device__ __forceinline__ void splitf16_2(float f0, float f1, unsigned& ph, unsigned& pl) {
    _Float16 h0 = (_Float16)f0, h1 = (_Float16)f1;
    float l0 = f0 - (float)h0, l1 = f1 - (float)h1;
    ph = packh2(h0, h1);
    pl = packh2((_Float16)l0, (_Float16)l1);
}

__device__ __forceinline__ void splitf16_8(const float4& a, const float4& b,
                                           uint4& uh, uint4& ul) {
    splitf16_2(a.x, a.y, uh.x, ul.x);
    splitf16_2(a.z, a.w, uh.y, ul.y);
    splitf16_2(b.x, b.y, uh.z, ul.z);
    splitf16_2(b.z, b.w, uh.w, ul.w);
}

// ---------- prep: 64 blocks x 256 thr, direct gather -> fp16 fragment panel ----------
// One uint2 (4 k-values, one n-col) per thread; no LDS, no barrier; W is L2/L3-warm.
__global__ __launch_bounds__(256) void k_prep(
    const float* __restrict__ Wq, const float* __restrict__ Wk,
    short* __restrict__ ws)
{
    const int gid  = blockIdx.x * 256 + threadIdx.x;   // 0..16383
    const int j0   = (gid & 1) * 4;
    const int lane = (gid >> 1) & 63;
    const int sub  = (gid >> 7) & 31;                  // 32-k subchunk
    const int nt   = gid >> 12;                        // n-tile 0..3
    const int n_g  = nt * 16 + (lane & 15);
    const int k_g  = sub * 32 + (lane >> 4) * 8 + j0;
    const float* __restrict__ src = (n_g < 32) ? Wq : Wk;
    const int col = n_g & 31;
    float f0 = src[(size_t)(k_g + 0) * DH + col];
    float f1 = src[(size_t)(k_g + 1) * DH + col];
    float f2 = src[(size_t)(k_g + 2) * DH + col];
    float f3 = src[(size_t)(k_g + 3) * DH + col];
    uint2 ph;
    ph.x = packh2((_Float16)f0, (_Float16)f1);         // RNE fp16
    ph.y = packh2((_Float16)f2, (_Float16)f3);
    *(uint2*)(ws + (size_t)gid * 4) = ph;              // gid*4 == (nt*32+sub)*512 + lane*8 + j0
}

// ---------- fused main: TB=32, fp16 2-pass MFMA, dist-2 prefetch; z folded into phase 4 ----------
#define TB 32
#define XS2 136  // x LDS row stride in shorts (128 data + 8 pad) = 272 B
#define QS 68    // qk row stride in floats

__global__ __launch_bounds__(256, 3) void k_main(
    const float* __restrict__ x, const float* __restrict__ bq,
    const float* __restrict__ bk, const short* __restrict__ ws,
    const float* __restrict__ w, float* __restrict__ out)
{
    __shared__ __align__(16) short xh_s[2][TB * XS2];
    __shared__ __align__(16) short xl_s[2][TB * XS2];
    __shared__ __align__(16) float qk_f[TB * QS];

    const int tid  = threadIdx.x;
    const int lane = tid & 63;
    const int wv   = __builtin_amdgcn_readfirstlane(tid >> 6);  // 0..3
    const int ln15 = lane & 15;
    const int g    = lane >> 4;                                  // 0..3
    const long t0  = (long)blockIdx.x * TB;

    const int nrow = wv * 16 + ln15;   // proj output column 0..63
    const float bias = (nrow < 32) ? bq[nrow] : bk[nrow - 32];

    // -------- Phase 1 (r4 champion, verbatim): C = x @ [Wq|Wk], dist-2 pipeline --------
    const int kq = tid & 15;
    const int mr = tid >> 4;

    f32x4 acc0 = {0.f, 0.f, 0.f, 0.f};   // tokens 0..15
    f32x4 acc1 = {0.f, 0.f, 0.f, 0.f};   // tokens 16..31

    const short* wpB = ws + (size_t)(wv * 32) * 512 + lane * 8;
    const float* xr0 = x + (t0 + mr) * (size_t)E_DIM + kq * 8;
    const float* xr1 = x + (t0 + mr + 16) * (size_t)E_DIM + kq * 8;

    float4 s0[4], s1[4];
    {
        float4 t0v = *(const float4*)(xr0 + 0), t1v = *(const float4*)(xr0 + 4);
        float4 t2v = *(const float4*)(xr1 + 0), t3v = *(const float4*)(xr1 + 4);
        s1[0] = *(const float4*)(xr0 + 128);
        s1[1] = *(const float4*)(xr0 + 132);
        s1[2] = *(const float4*)(xr1 + 128);
        s1[3] = *(const float4*)(xr1 + 132);
        uint4 uh, ul;
        splitf16_8(t0v, t1v, uh, ul);
        *(uint4*)&xh_s[0][mr * XS2 + kq * 8] = uh;
        *(uint4*)&xl_s[0][mr * XS2 + kq * 8] = ul;
        splitf16_8(t2v, t3v, uh, ul);
        *(uint4*)&xh_s[0][(mr + 16) * XS2 + kq * 8] = uh;
        *(uint4*)&xl_s[0][(mr + 16) * XS2 + kq * 8] = ul;
    }

#pragma unroll
    for (int p = 0; p < 8; ++p) {
        __syncthreads();
        if (p < 6) {
            float4* d = (p & 1) ? s1 : s0;
            d[0] = *(const float4*)(xr0 + (p + 2) * 128);
            d[1] = *(const float4*)(xr0 + (p + 2) * 128 + 4);
            d[2] = *(const float4*)(xr1 + (p + 2) * 128);
            d[3] = *(const float4*)(xr1 + (p + 2) * 128 + 4);
        }
        f16x8 bfr[4];
#pragma unroll
        for (int j = 0; j < 4; ++j)
            bfr[j] = *(const f16x8*)(wpB + (size_t)(p * 4 + j) * 512);
#pragma unroll
        for (int j = 0; j < 4; ++j) {
            f16x8 ah0 = *(const f16x8*)&xh_s[p & 1][ln15 * XS2 + j * 32 + g * 8];
            f16x8 al0 = *(const f16x8*)&xl_s[p & 1][ln15 * XS2 + j * 32 + g * 8];
            f16x8 ah1 = *(const f16x8*)&xh_s[p & 1][(ln15 + 16) * XS2 + j * 32 + g * 8];
            f16x8 al1 = *(const f16x8*)&xl_s[p & 1][(ln15 + 16) * XS2 + j * 32 + g * 8];
            acc0 = __builtin_amdgcn_mfma_f32_16x16x32_f16(ah0, bfr[j], acc0, 0, 0, 0);
            acc0 = __builtin_amdgcn_mfma_f32_16x16x32_f16(al0, bfr[j], acc0, 0, 0, 0);
            acc1 = __builtin_amdgcn_mfma_f32_16x16x32_f16(ah1, bfr[j], acc1, 0, 0, 0);
            acc1 = __builtin_amdgcn_mfma_f32_16x16x32_f16(al1, bfr[j], acc1, 0, 0, 0);
        }
        if (p < 7) {
            const float4* s = ((p + 1) & 1) ? s1 : s0;
            uint4 uh, ul;
            splitf16_8(s[0], s[1], uh, ul);
            *(uint4*)&xh_s[(p + 1) & 1][mr * XS2 + kq * 8] = uh;
            *(uint4*)&xl_s[(p + 1) & 1][mr * XS2 + kq * 8] = ul;
            splitf16_8(s[2], s[3], uh, ul);
            *(uint4*)&xh_s[(p + 1) & 1][(mr + 16) * XS2 + kq * 8] = uh;
            *(uint4*)&xl_s[(p + 1) & 1][(mr + 16) * XS2 + kq * 8] = ul;
        }
    }

    // issue feature-w fp32 fragment loads; phase-2 writes + barrier cover their latency
    float4 wfa[4], wfb[4];
#pragma unroll
    for (int i = 0; i < 4; ++i) {
        const int nf = (wv * 4 + i) * 16 + ln15;    // feature 0..255
        wfa[i] = *(const float4*)(w + (size_t)nf * DH + g * 8);
        wfb[i] = *(const float4*)(w + (size_t)nf * DH + g * 8 + 4);
    }

    // -------- Phase 2: +bias -> qk LDS (C/D layout: row(tok)=g*4+r, col=ln15); ONE barrier --------
#pragma unroll
    for (int r = 0; r < 4; ++r) {
        qk_f[(g * 4 + r) * QS + nrow]        = acc0[r] + bias;
        qk_f[(16 + g * 4 + r) * QS + nrow]   = acc1[r] + bias;
    }
    __syncthreads();

    // -------- Phase 4: A = split(q+k) read directly from qk_f; lnA via FMA + shfl --------
    const float LOG2E = 1.4426950408889634f;
    f16x8 a_h[2], a_l[2];
    float pwv[2];
#pragma unroll
    for (int mt = 0; mt < 2; ++mt) {
        const int row = mt * 16 + ln15;
        float4 qlo = *(const float4*)&qk_f[row * QS + g * 8];
        float4 qhi = *(const float4*)&qk_f[row * QS + g * 8 + 4];
        float4 klo = *(const float4*)&qk_f[row * QS + 32 + g * 8];
        float4 khi = *(const float4*)&qk_f[row * QS + 32 + g * 8 + 4];
        float4 zlo = {qlo.x + klo.x, qlo.y + klo.y, qlo.z + klo.z, qlo.w + klo.w};
        float4 zhi = {qhi.x + khi.x, qhi.y + khi.y, qhi.z + khi.z, qhi.w + khi.w};
        uint4 uh, ul;
        splitf16_8(zlo, zhi, uh, ul);
        a_h[mt] = __builtin_bit_cast(f16x8, uh);
        a_l[mt] = __builtin_bit_cast(f16x8, ul);
        float pw = qlo.x*qlo.x + qlo.y*qlo.y + qlo.z*qlo.z + qlo.w*qlo.w
                 + qhi.x*qhi.x + qhi.y*qhi.y + qhi.z*qhi.z + qhi.w*qhi.w
                 + klo.x*klo.x + klo.y*klo.y + klo.z*klo.z + klo.w*klo.w
                 + khi.x*khi.x + khi.y*khi.y + khi.z*khi.z + khi.w*khi.w;
        pw += __shfl_xor(pw, 16);          // combine g-slices (token = row, lanes differ in g)
        pw += __shfl_xor(pw, 32);
        pwv[mt] = pw;
    }
    // redistribute: lnA for token g*4+r lives in lanes with ln15 == g*4+r
    float lnAv[2][4];
#pragma unroll
    for (int mt = 0; mt < 2; ++mt)
#pragma unroll
        for (int r = 0; r < 4; ++r)
            lnAv[mt][r] = -0.5f * LOG2E * __shfl(pwv[mt], g * 4 + r);

    // -------- Phase 4b: S = z @ w^T (fp16 2-pass); wave wv: features wv*64.. --------
    f32x4 facc[4][2];
#pragma unroll
    for (int i = 0; i < 4; ++i)
#pragma unroll
        for (int mt = 0; mt < 2; ++mt) facc[i][mt] = (f32x4){0.f,0.f,0.f,0.f};

#pragma unroll
    for (int i = 0; i < 4; ++i) {
        uint4 uw;
        uw.x = packh2((_Float16)wfa[i].x, (_Float16)wfa[i].y);
        uw.y = packh2((_Float16)wfa[i].z, (_Float16)wfa[i].w);
        uw.z = packh2((_Float16)wfb[i].x, (_Float16)wfb[i].y);
        uw.w = packh2((_Float16)wfb[i].z, (_Float16)wfb[i].w);
        f16x8 w8 = __builtin_bit_cast(f16x8, uw);
#pragma unroll
        for (int mt = 0; mt < 2; ++mt) {
            facc[i][mt] = __builtin_amdgcn_mfma_f32_16x16x32_f16(a_h[mt], w8, facc[i][mt], 0, 0, 0);
            facc[i][mt] = __builtin_amdgcn_mfma_f32_16x16x32_f16(a_l[mt], w8, facc[i][mt], 0, 0, 0);
        }
    }

    // -------- Phase 5: R = 0.5*(exp2(a+s') + exp2(a-s')), prescaled by log2e --------
#pragma unroll
    for (int i = 0; i < 4; ++i) {
        const int n = (wv * 4 + i) * 16 + ln15;
#pragma unroll
        for (int mt = 0; mt < 2; ++mt) {
#pragma unroll
            for (int r = 0; r < 4; ++r) {
                float s = facc[i][mt][r] * LOG2E;
                float R = 0.5f * (__builtin_amdgcn_exp2f(lnAv[mt][r] + s)
                                + __builtin_amdgcn_exp2f(lnAv[mt][r] - s));
                __builtin_nontemporal_store(R, &out[(t0 + mt * 16 + g * 4 + r) * M_FEAT + n]);
            }
        }
    }
}

extern "C" void kernel_launch(void* const* d_in, const int* in_sizes, int n_in,
                              void* d_out, int out_size, void* d_ws, size_t ws_size,
                              hipStream_t stream) {
    const float* x  = (const float*)d_in[0];
    const float* Wq = (const float*)d_in[1];
    const float* bq = (const float*)d_in[2];
    const float* Wk = (const float*)d_in[3];
    const float* bk = (const float*)d_in[4];
    // d_in[5], d_in[6] = Wv, bv: dead in the reference
    const float* w  = (const float*)d_in[7];
    float* out = (float*)d_out;
    short* ws  = (short*)d_ws;   // 128 KB used (single fp16 weight panel)

    k_prep<<<dim3(64), dim3(256), 0, stream>>>(Wq, Wk, ws);
    k_main<<<dim3(BT / TB), dim3(256), 0, stream>>>(x, bq, bk, ws, w, out);
}